// Round 2
// baseline (4630.043 us; speedup 1.0000x reference)
//
#include <hip/hip_runtime.h>
#include <math.h>

// Sizes
// B=8, IN=2, N=512, T_IN=13, RC=DC=32, SC=256, EC=512, EMB=16, DATT=16, L=8

__global__ void k_init_norm(float* normP){
    int t = threadIdx.x; // 64 threads
    normP[t] = (t < 32) ? 1.0f : 0.0f;
}

// qe/ke[l][n][16] = bias + W[:,32:48] @ gat[:,n]
__global__ void k_emb(const float* __restrict__ qw, const float* __restrict__ qb,
                      const float* __restrict__ kw, const float* __restrict__ kb,
                      const float* __restrict__ gat, float* __restrict__ qe, float* __restrict__ ke){
    int idx = blockIdx.x*256 + threadIdx.x;
    const int total = 8*512*16;
    if (idx >= 2*total) return;
    bool isK = idx >= total;
    int id = isK ? idx - total : idx;
    int dq = id & 15; int n = (id >> 4) & 511; int l = id >> 13;
    const float* w = isK ? kw : qw;
    const float* bi = isK ? kb : qb;
    float acc = bi[l*16 + dq];
    const float* wrow = w + (l*16 + dq)*48 + 32;
    #pragma unroll
    for (int e = 0; e < 16; e++) acc += wrow[e] * gat[e*512 + n];
    (isK ? ke : qe)[(l*512 + n)*16 + dq] = acc;
}

// x0[b][t][c][n] = start pw
__global__ void k_start(const float* __restrict__ inp, const float* __restrict__ sw,
                        const float* __restrict__ sb, float* __restrict__ x0){
    int idx = blockIdx.x*256 + threadIdx.x;
    if (idx >= 8*13*32*512) return;
    int n = idx & 511; int c = (idx >> 9) & 31; int r = idx >> 14;
    int t = r % 13; int b = r / 13;
    float v0 = inp[((b*2 + 0)*512 + n)*13 + t];
    float v1 = inp[((b*2 + 1)*512 + n)*13 + t];
    x0[idx] = sb[c] + sw[c*2 + 0]*v0 + sw[c*2 + 1]*v1;
}

// gated dilated conv + q/k projections. xin layout [b][Tin][c][n] (pre-BN raw; normP applied on read)
// writes xc [b][t][c][n], xt [b][t][n][c], q (scaled by 0.25), k
__global__ __launch_bounds__(128) void k_gated(
    const float* __restrict__ xin, int Tin, int d, int Tout,
    const float* __restrict__ normP,
    const float* __restrict__ fw, const float* __restrict__ fb,
    const float* __restrict__ gw, const float* __restrict__ gb,
    const float* __restrict__ qw, const float* __restrict__ kw,   // [16][48] rows (use cols 0..31)
    const float* __restrict__ qe, const float* __restrict__ ke,   // [512][16]
    float* __restrict__ xc, float* __restrict__ xt,
    float* __restrict__ qo, float* __restrict__ ko)
{
    __shared__ float xs[2][32][128];
    __shared__ float fws[2048];
    __shared__ float gws[2048];
    __shared__ float qws[512];
    __shared__ float kws[512];
    int tid = threadIdx.x;
    int nb = blockIdx.x, t = blockIdx.y, b = blockIdx.z;
    int n0 = nb*128;
    for (int e = tid; e < 2048; e += 128){ fws[e] = fw[e]; gws[e] = gw[e]; }
    for (int e = tid; e < 512; e += 128){
        qws[e] = qw[(e >> 5)*48 + (e & 31)];
        kws[e] = kw[(e >> 5)*48 + (e & 31)];
    }
    const float* A = normP; const float* Bc = normP + 32;
    for (int e = tid; e < 2*32*128; e += 128){
        int kwi = e >> 12; int c = (e >> 7) & 31; int nn = e & 127;
        float v = xin[((size_t)(b*Tin + t + kwi*d)*32 + c)*512 + n0 + nn];
        xs[kwi][c][nn] = A[c]*v + Bc[c];
    }
    __syncthreads();
    int n = n0 + tid;
    float xr[32];
    #pragma unroll
    for (int c = 0; c < 32; c++){
        float fa = fb[c], ga = gb[c];
        #pragma unroll
        for (int r = 0; r < 32; r++){
            float x0v = xs[0][r][tid], x1v = xs[1][r][tid];
            fa += fws[(c*32+r)*2]*x0v + fws[(c*32+r)*2+1]*x1v;
            ga += gws[(c*32+r)*2]*x0v + gws[(c*32+r)*2+1]*x1v;
        }
        float v = tanhf(fa) * (1.0f/(1.0f + __expf(-ga)));
        xr[c] = v;
        xc[((size_t)(b*Tout + t)*32 + c)*512 + n] = v;
    }
    // transposed copy for the attention-apply kernel
    float* xtrow = xt + (((size_t)(b*Tout + t)*512) + n)*32;
    #pragma unroll
    for (int c = 0; c < 32; c += 4)
        *(float4*)(xtrow + c) = make_float4(xr[c], xr[c+1], xr[c+2], xr[c+3]);
    float qv[16], kv[16];
    #pragma unroll
    for (int j = 0; j < 16; j++){ qv[j] = qe[n*16 + j]; kv[j] = ke[n*16 + j]; }
    #pragma unroll
    for (int j = 0; j < 16; j++){
        float a = qv[j], bb2 = kv[j];
        #pragma unroll
        for (int c = 0; c < 32; c++){ a += qws[j*32 + c]*xr[c]; bb2 += kws[j*32 + c]*xr[c]; }
        qv[j] = a * 0.25f;   // fold softmax scale into q
        kv[j] = bb2;
    }
    float* qrow = qo + ((size_t)(b*Tout + t)*512 + n)*16;
    float* krow = ko + ((size_t)(b*Tout + t)*512 + n)*16;
    #pragma unroll
    for (int j = 0; j < 16; j += 4){
        *(float4*)(qrow + j) = make_float4(qv[j], qv[j+1], qv[j+2], qv[j+3]);
        *(float4*)(krow + j) = make_float4(kv[j], kv[j+1], kv[j+2], kv[j+3]);
    }
}

// skip accumulation: only last time column matters. skip[b][oc][n] += sb + sw @ xc[:, lastcol]
__global__ void k_skip(const float* __restrict__ xc, int Tout,
                       const float* __restrict__ sw, const float* __restrict__ sb,
                       float* __restrict__ skip){
    int idx = blockIdx.x*256 + threadIdx.x; // 8*256*512
    int n = idx & 511; int oc = (idx >> 9) & 255; int b = idx >> 17;
    const float* base = xc + ((size_t)(b*Tout + (Tout-1))*32)*512 + n;
    float acc = sb[oc];
    #pragma unroll
    for (int c = 0; c < 32; c++) acc += sw[oc*32 + c] * base[c*512];
    skip[idx] += acc;
}

// per-row softmax stats. LDS-free: thread = (row, wsub); 4 threads per row, 128 keys each.
__global__ __launch_bounds__(256, 4) void k_att_stats2(
    const float* __restrict__ qb_, const float* __restrict__ kb_, int T,
    float* __restrict__ rowmax, float* __restrict__ invZ)
{
    int tid = threadIdx.x;
    int chunk = blockIdx.x, t = blockIdx.y, b = blockIdx.z;
    size_t bt = (size_t)(b*T + t);
    int vrow = chunk*64 + (tid >> 2);
    int wsub = tid & 3;
    const float* qrow = qb_ + (bt*512 + vrow)*16;
    float q[16];
    #pragma unroll
    for (int j = 0; j < 16; j += 4){
        float4 qv = *(const float4*)(qrow + j);
        q[j] = qv.x; q[j+1] = qv.y; q[j+2] = qv.z; q[j+3] = qv.w;
    }
    const float* kbase = kb_ + bt*512*16;
    float mx = -1e30f, sm = 0.0f;
    int w0 = wsub*128;
    for (int w = w0; w < w0 + 128; w++){
        const float* kr = kbase + w*16;
        float s = 0.0f;
        #pragma unroll
        for (int j = 0; j < 16; j += 4){
            float4 kv = *(const float4*)(kr + j);
            s += q[j]*kv.x + q[j+1]*kv.y + q[j+2]*kv.z + q[j+3]*kv.w;
        }
        if (s > mx){ sm *= __expf(mx - s); mx = s; }
        sm += __expf(s - mx);
    }
    #pragma unroll
    for (int dd = 1; dd <= 2; dd <<= 1){
        float mo = __shfl_xor(mx, dd);
        float so = __shfl_xor(sm, dd);
        float mn = fmaxf(mx, mo);
        sm = sm*__expf(mx - mn) + so*__expf(mo - mn);
        mx = mn;
    }
    if (wsub == 0){
        rowmax[bt*512 + vrow] = mx;
        invZ[bt*512 + vrow] = 1.0f / sm;
    }
}

// fused att apply + gmlp + residual -> y (pre-BN), layout [b][Tout][c][n]
// LDS-free: thread = (w, vsub); 4 threads per output node, 128 v's each, shuffle-merge.
__global__ __launch_bounds__(256, 4) void k_att_apply2(
    const float* __restrict__ qb_, const float* __restrict__ kb_,
    const float* __restrict__ xt,
    const float* __restrict__ rowmax, const float* __restrict__ invZ,
    const float* __restrict__ xin, int Tin, int d, int Tout,
    const float* __restrict__ normP,
    const float* __restrict__ gw, const float* __restrict__ gb,
    float* __restrict__ y)
{
    int tid = threadIdx.x;
    int chunk = blockIdx.x, t = blockIdx.y, b = blockIdx.z;
    size_t bt = (size_t)(b*Tout + t);
    int w = chunk*64 + (tid >> 2);
    int vsub = tid & 3;
    const float* krow = kb_ + (bt*512 + w)*16;
    float kr[16];
    #pragma unroll
    for (int j = 0; j < 16; j += 4){
        float4 kv = *(const float4*)(krow + j);
        kr[j] = kv.x; kr[j+1] = kv.y; kr[j+2] = kv.z; kr[j+3] = kv.w;
    }
    const float* qbase = qb_ + bt*512*16;
    const float* xbase = xt + bt*512*32;
    const float* rm = rowmax + bt*512;
    const float* iz = invZ + bt*512;
    float acc[32];
    #pragma unroll
    for (int c = 0; c < 32; c++) acc[c] = 0.0f;
    int v0 = vsub*128;
    for (int v = v0; v < v0 + 128; v++){
        const float* qr = qbase + (size_t)v*16;
        float s = 0.0f;
        #pragma unroll
        for (int j = 0; j < 16; j += 4){
            float4 qv = *(const float4*)(qr + j);
            s += qv.x*kr[j] + qv.y*kr[j+1] + qv.z*kr[j+2] + qv.w*kr[j+3];
        }
        float p = __expf(s - rm[v]) * iz[v];
        const float* xr = xbase + (size_t)v*32;
        #pragma unroll
        for (int c = 0; c < 32; c += 4){
            float4 xv = *(const float4*)(xr + c);
            acc[c]   += xv.x*p;
            acc[c+1] += xv.y*p;
            acc[c+2] += xv.z*p;
            acc[c+3] += xv.w*p;
        }
    }
    // butterfly-merge across the 4 vsub lanes (all lanes end with the full sum)
    #pragma unroll
    for (int c = 0; c < 32; c++){
        acc[c] += __shfl_xor(acc[c], 1);
        acc[c] += __shfl_xor(acc[c], 2);
    }
    // gmlp + residual: each vsub lane computes 8 of the 32 output channels
    const float* A = normP; const float* Bc = normP + 32;
    const float* xw = xbase + (size_t)w*32;
    float xwr[32];
    #pragma unroll
    for (int c = 0; c < 32; c += 4){
        float4 xv = *(const float4*)(xw + c);
        xwr[c] = xv.x; xwr[c+1] = xv.y; xwr[c+2] = xv.z; xwr[c+3] = xv.w;
    }
    #pragma unroll
    for (int oi = 0; oi < 8; oi++){
        int o = vsub*8 + oi;
        float a = gb[o];
        const float* g0 = gw + o*64;
        #pragma unroll
        for (int c = 0; c < 32; c++) a += g0[c]*xwr[c] + g0[32 + c]*acc[c];
        float res = A[o]*xin[((size_t)(b*Tin + t + d)*32 + o)*512 + w] + Bc[o];
        y[(bt*32 + o)*512 + w] = a + res;
    }
}

// BN batch stats -> scale/shift for next layer's reads
__global__ __launch_bounds__(256) void k_bn(const float* __restrict__ y, int Tout,
                                            const float* __restrict__ g, const float* __restrict__ bb,
                                            float* __restrict__ normPout){
    int c = blockIdx.x; int tid = threadIdx.x;
    int cnt = 8*Tout*512;
    double s = 0.0, s2 = 0.0;
    for (int e = tid; e < cnt; e += 256){
        int n = e & 511; int btq = e >> 9;
        float v = y[((size_t)btq*32 + c)*512 + n];
        s += v; s2 += (double)v*v;
    }
    __shared__ double sh[2][4];
    for (int off = 32; off; off >>= 1){ s += __shfl_down(s, off); s2 += __shfl_down(s2, off); }
    int w = tid >> 6;
    if ((tid & 63) == 0){ sh[0][w] = s; sh[1][w] = s2; }
    __syncthreads();
    if (tid == 0){
        double S = 0.0, S2 = 0.0;
        #pragma unroll
        for (int i = 0; i < 4; i++){ S += sh[0][i]; S2 += sh[1][i]; }
        float m = (float)(S/cnt);
        float var = (float)(S2/cnt) - m*m;
        float Aa = g[c]*rsqrtf(var + 1e-5f);
        normPout[c] = Aa;
        normPout[32 + c] = bb[c] - m*Aa;
    }
}

// final: relu(skip) -> relu(end1) -> end2
__global__ __launch_bounds__(256) void k_end(const float* __restrict__ skip,
                                             const float* __restrict__ w1, const float* __restrict__ b1,
                                             const float* __restrict__ w2, const float* __restrict__ b2,
                                             float* __restrict__ out){
    __shared__ float sk[16][260];
    __shared__ float hs[512][17];
    int tid = threadIdx.x; int ng = blockIdx.x; int b = blockIdx.y;
    int nb = ng*16;
    for (int e = tid; e < 4096; e += 256){
        int oc = e >> 4, nn = e & 15;
        float v = skip[((size_t)b*256 + oc)*512 + nb + nn];
        sk[nn][oc] = fmaxf(v, 0.0f);
    }
    __syncthreads();
    float a0[16], a1[16];
    #pragma unroll
    for (int i = 0; i < 16; i++){ a0[i] = b1[tid]; a1[i] = b1[tid + 256]; }
    for (int c = 0; c < 256; c += 4){
        float4 wA = *(const float4*)(w1 + tid*256 + c);
        float4 wB = *(const float4*)(w1 + (tid + 256)*256 + c);
        #pragma unroll
        for (int nn = 0; nn < 16; nn++){
            float4 s4 = *(const float4*)(&sk[nn][c]);
            a0[nn] += wA.x*s4.x + wA.y*s4.y + wA.z*s4.z + wA.w*s4.w;
            a1[nn] += wB.x*s4.x + wB.y*s4.y + wB.z*s4.z + wB.w*s4.w;
        }
    }
    #pragma unroll
    for (int nn = 0; nn < 16; nn++){
        hs[tid][nn] = fmaxf(a0[nn], 0.0f);
        hs[tid + 256][nn] = fmaxf(a1[nn], 0.0f);
    }
    __syncthreads();
    if (tid < 192){
        int od = tid >> 4, nn = tid & 15;
        float acc = b2[od];
        for (int o = 0; o < 512; o++) acc += w2[od*512 + o]*hs[o][nn];
        out[((size_t)b*12 + od)*512 + nb + nn] = acc;
    }
}

extern "C" void kernel_launch(void* const* d_in, const int* in_sizes, int n_in,
                              void* d_out, int out_size, void* d_ws, size_t ws_size,
                              hipStream_t stream)
{
    (void)in_sizes; (void)n_in; (void)out_size; (void)ws_size;
    const float* input  = (const float*)d_in[0];
    const float* gat    = (const float*)d_in[1];
    const float* start_w= (const float*)d_in[2];
    const float* start_b= (const float*)d_in[3];
    const float* filt_w = (const float*)d_in[4];
    const float* filt_b = (const float*)d_in[5];
    const float* gate_w = (const float*)d_in[6];
    const float* gate_b = (const float*)d_in[7];
    const float* skip_w = (const float*)d_in[8];
    const float* skip_b = (const float*)d_in[9];
    const float* q_w    = (const float*)d_in[10];
    const float* q_b    = (const float*)d_in[11];
    const float* k_w    = (const float*)d_in[12];
    const float* k_b    = (const float*)d_in[13];
    const float* gmlp_w = (const float*)d_in[14];
    const float* gmlp_b = (const float*)d_in[15];
    const float* bn_g   = (const float*)d_in[16];
    const float* bn_b   = (const float*)d_in[17];
    const float* end1_w = (const float*)d_in[18];
    const float* end1_b = (const float*)d_in[19];
    const float* end2_w = (const float*)d_in[20];
    const float* end2_b = (const float*)d_in[21];
    float* out = (float*)d_out;

    float* W = (float*)d_ws;
    size_t off = 0;
    float* bufA = W + off; off += (size_t)8*13*32*512;
    float* bufB = W + off; off += (size_t)8*13*32*512;
    float* xc   = W + off; off += (size_t)8*12*32*512;
    float* xt   = W + off; off += (size_t)8*12*512*32;
    float* qbuf = W + off; off += (size_t)8*12*512*16;
    float* kbuf = W + off; off += (size_t)8*12*512*16;
    float* rowm = W + off; off += (size_t)8*12*512;
    float* izb  = W + off; off += (size_t)8*12*512;
    float* skip = W + off; off += (size_t)8*256*512;
    float* qe   = W + off; off += (size_t)8*512*16;
    float* ke   = W + off; off += (size_t)8*512*16;
    float* normP= W + off; off += (size_t)9*64;

    hipMemsetAsync(skip, 0, (size_t)8*256*512*sizeof(float), stream);
    k_init_norm<<<1, 64, 0, stream>>>(normP);
    k_emb<<<512, 256, 0, stream>>>(q_w, q_b, k_w, k_b, gat, qe, ke);
    k_start<<<6656, 256, 0, stream>>>(input, start_w, start_b, bufA);

    const int Tin[8] = {13,12,10,9,7,6,4,3};
    const int Dd[8]  = {1,2,1,2,1,2,1,2};
    float* xin = bufA; float* yb = bufB;
    for (int i = 0; i < 8; i++){
        int Ti = Tin[i], d = Dd[i], To = Ti - d;
        k_gated<<<dim3(4, To, 8), 128, 0, stream>>>(xin, Ti, d, To, normP + i*64,
            filt_w + i*2048, filt_b + i*32, gate_w + i*2048, gate_b + i*32,
            q_w + i*768, k_w + i*768, qe + i*8192, ke + i*8192, xc, xt, qbuf, kbuf);
        k_skip<<<4096, 256, 0, stream>>>(xc, To, skip_w + i*8192, skip_b + i*256, skip);
        if (i < 7){
            k_att_stats2<<<dim3(8, To, 8), 256, 0, stream>>>(qbuf, kbuf, To, rowm, izb);
            k_att_apply2<<<dim3(8, To, 8), 256, 0, stream>>>(qbuf, kbuf, xt, rowm, izb,
                xin, Ti, d, To, normP + i*64, gmlp_w + i*2048, gmlp_b + i*32, yb);
            k_bn<<<32, 256, 0, stream>>>(yb, To, bn_g + i*32, bn_b + i*32, normP + (i+1)*64);
            float* tmp = xin; xin = yb; yb = tmp;
        }
    }
    k_end<<<dim3(32, 8), 256, 0, stream>>>(skip, end1_w, end1_b, end2_w, end2_b, out);
}

// Round 3
// 1828.624 us; speedup vs baseline: 2.5320x; 2.5320x over previous
//
#include <hip/hip_runtime.h>
#include <math.h>

// Sizes: B=8, IN=2, N=512, T_IN=13, RC=DC=32, SC=256, EC=512, EMB=16, DATT=16, L=8

__global__ void k_init_norm(float* normP){
    int t = threadIdx.x; // 64 threads
    normP[t] = (t < 32) ? 1.0f : 0.0f;
}

// qe/ke[l][n][16] = bias + W[:,32:48] @ gat[:,n]
__global__ void k_emb(const float* __restrict__ qw, const float* __restrict__ qb,
                      const float* __restrict__ kw, const float* __restrict__ kb,
                      const float* __restrict__ gat, float* __restrict__ qe, float* __restrict__ ke){
    int idx = blockIdx.x*256 + threadIdx.x;
    const int total = 8*512*16;
    if (idx >= 2*total) return;
    bool isK = idx >= total;
    int id = isK ? idx - total : idx;
    int dq = id & 15; int n = (id >> 4) & 511; int l = id >> 13;
    const float* w = isK ? kw : qw;
    const float* bi = isK ? kb : qb;
    float acc = bi[l*16 + dq];
    const float* wrow = w + (l*16 + dq)*48 + 32;
    #pragma unroll
    for (int e = 0; e < 16; e++) acc += wrow[e] * gat[e*512 + n];
    (isK ? ke : qe)[(l*512 + n)*16 + dq] = acc;
}

// x0[b][t][c][n] = start pw
__global__ void k_start(const float* __restrict__ inp, const float* __restrict__ sw,
                        const float* __restrict__ sb, float* __restrict__ x0){
    int idx = blockIdx.x*256 + threadIdx.x;
    if (idx >= 8*13*32*512) return;
    int n = idx & 511; int c = (idx >> 9) & 31; int r = idx >> 14;
    int t = r % 13; int b = r / 13;
    float v0 = inp[((b*2 + 0)*512 + n)*13 + t];
    float v1 = inp[((b*2 + 1)*512 + n)*13 + t];
    x0[idx] = sb[c] + sw[c*2 + 0]*v0 + sw[c*2 + 1]*v1;
}

// gated dilated conv + q/k projections. x from global into regs; weights in LDS.
// writes xt [b][t][n][c], q (scaled 0.25), k
__global__ __launch_bounds__(256) void k_gated(
    const float* __restrict__ xin, int Tin, int d, int Tout,
    const float* __restrict__ normP,
    const float* __restrict__ fw, const float* __restrict__ fb,
    const float* __restrict__ gw, const float* __restrict__ gb,
    const float* __restrict__ qw, const float* __restrict__ kw,
    const float* __restrict__ qe, const float* __restrict__ ke,
    float* __restrict__ xt, float* __restrict__ qo, float* __restrict__ ko)
{
    __shared__ float fws[2048];
    __shared__ float gws[2048];
    __shared__ float qws[512];
    __shared__ float kws[512];
    int tid = threadIdx.x;
    int chunk = blockIdx.x, t = blockIdx.y, b = blockIdx.z;
    int n = chunk*256 + tid;
    for (int e = tid; e < 2048; e += 256){ fws[e] = fw[e]; gws[e] = gw[e]; }
    for (int e = tid; e < 512; e += 256){
        qws[e] = qw[(e >> 5)*48 + (e & 31)];
        kws[e] = kw[(e >> 5)*48 + (e & 31)];
    }
    __syncthreads();
    float x0[32], x1[32];
    const float* base0 = xin + ((size_t)(b*Tin + t)*32)*512 + n;
    const float* base1 = xin + ((size_t)(b*Tin + t + d)*32)*512 + n;
    #pragma unroll
    for (int c = 0; c < 32; c++){
        float A = normP[c], Bc = normP[32 + c];
        x0[c] = A*base0[c*512] + Bc;
        x1[c] = A*base1[c*512] + Bc;
    }
    float xv[32];
    #pragma unroll
    for (int c = 0; c < 32; c++){
        float fa = fb[c], ga = gb[c];
        #pragma unroll
        for (int r = 0; r < 32; r++){
            fa += fws[(c*32+r)*2]*x0[r] + fws[(c*32+r)*2+1]*x1[r];
            ga += gws[(c*32+r)*2]*x0[r] + gws[(c*32+r)*2+1]*x1[r];
        }
        float e2 = __expf(2.0f*fa);
        float th = 1.0f - 2.0f/(e2 + 1.0f);      // tanh
        float sg = 1.0f/(1.0f + __expf(-ga));    // sigmoid
        xv[c] = th*sg;
    }
    float* xtrow = xt + (((size_t)(b*Tout + t)*512) + n)*32;
    #pragma unroll
    for (int c = 0; c < 32; c += 4)
        *(float4*)(xtrow + c) = make_float4(xv[c], xv[c+1], xv[c+2], xv[c+3]);
    float qv[16], kv[16];
    #pragma unroll
    for (int j = 0; j < 16; j += 4){
        float4 a = *(const float4*)(qe + n*16 + j);
        float4 bb = *(const float4*)(ke + n*16 + j);
        qv[j]=a.x; qv[j+1]=a.y; qv[j+2]=a.z; qv[j+3]=a.w;
        kv[j]=bb.x; kv[j+1]=bb.y; kv[j+2]=bb.z; kv[j+3]=bb.w;
    }
    #pragma unroll
    for (int j = 0; j < 16; j++){
        float a = qv[j], bb2 = kv[j];
        #pragma unroll
        for (int c = 0; c < 32; c++){ a += qws[j*32 + c]*xv[c]; bb2 += kws[j*32 + c]*xv[c]; }
        qv[j] = a * 0.25f;   // fold softmax scale
        kv[j] = bb2;
    }
    float* qrow = qo + ((size_t)(b*Tout + t)*512 + n)*16;
    float* krow = ko + ((size_t)(b*Tout + t)*512 + n)*16;
    #pragma unroll
    for (int j = 0; j < 16; j += 4){
        *(float4*)(qrow + j) = make_float4(qv[j], qv[j+1], qv[j+2], qv[j+3]);
        *(float4*)(krow + j) = make_float4(kv[j], kv[j+1], kv[j+2], kv[j+3]);
    }
}

// skip accumulation: only last time column matters.
__global__ void k_skip(const float* __restrict__ xt, int Tout,
                       const float* __restrict__ sw, const float* __restrict__ sb,
                       float* __restrict__ skip){
    int idx = blockIdx.x*256 + threadIdx.x; // (b,oc,n), n fastest
    int n = idx & 511; int oc = (idx >> 9) & 255; int b = idx >> 17;
    const float* xr = xt + (((size_t)(b*Tout + (Tout-1))*512) + n)*32;
    const float* wr = sw + oc*32;
    float acc = sb[oc];
    #pragma unroll
    for (int c = 0; c < 32; c += 4){
        float4 xv = *(const float4*)(xr + c);
        acc += wr[c]*xv.x + wr[c+1]*xv.y + wr[c+2]*xv.z + wr[c+3]*xv.w;
    }
    skip[idx] += acc;
}

// Fused attention: per (vchunk of 128 v's, bt). Phase1: Z[v] over all 512 w (no max-sub).
// Phase2: PV partials for all 512 w over this v-chunk -> pbuf[vc].
__global__ __launch_bounds__(256) void k_att(
    const float* __restrict__ qbuf, const float* __restrict__ kbuf,
    const float* __restrict__ xt, float* __restrict__ pbuf, int Tout)
{
    // LDS union: ks[512][16] @0 (reused as xz[128][32] @0), qs[128][16] @8192, izs[128] @10240
    __shared__ float lds[10368];
    int tid = threadIdx.x;
    int vc = blockIdx.x, t = blockIdx.y, b = blockIdx.z;
    size_t bt = (size_t)(b*Tout + t);
    const float* kb_ = kbuf + bt*8192;
    const float* qb_ = qbuf + bt*8192;
    for (int e = tid; e < 2048; e += 256)
        ((float4*)&lds[0])[e] = ((const float4*)kb_)[e];
    for (int e = tid; e < 512; e += 256)
        ((float4*)&lds[8192])[e] = ((const float4*)(qb_ + vc*2048))[e];
    __syncthreads();
    // phase 1: Z for the 128 v-rows of this chunk
    {
        int vl = tid >> 1, wsub = tid & 1;
        const float4* q4 = (const float4*)(qb_ + (vc*128 + vl)*16);
        float4 qA = q4[0], qB = q4[1], qC = q4[2], qD = q4[3];
        float z = 0.0f;
        int w0 = wsub*256;
        for (int i = 0; i < 256; i++){
            const float4* k4 = (const float4*)&lds[(w0 + i)*16];
            float4 kA = k4[0], kB = k4[1], kC = k4[2], kD = k4[3];
            float s = qA.x*kA.x + qA.y*kA.y + qA.z*kA.z + qA.w*kA.w
                    + qB.x*kB.x + qB.y*kB.y + qB.z*kB.z + qB.w*kB.w
                    + qC.x*kC.x + qC.y*kC.y + qC.z*kC.z + qC.w*kC.w
                    + qD.x*kD.x + qD.y*kD.y + qD.z*kD.z + qD.w*kD.w;
            z += __expf(fminf(s, 80.0f));
        }
        z += __shfl_xor(z, 1);
        if (wsub == 0) lds[10240 + vl] = 1.0f/z;
    }
    // k-rows for this thread's two w's (from global, L1/L2-hot)
    float kr0[16], kr1[16];
    {
        const float4* k40 = (const float4*)(kb_ + tid*16);
        const float4* k41 = (const float4*)(kb_ + (tid + 256)*16);
        #pragma unroll
        for (int j = 0; j < 4; j++){
            float4 a = k40[j], c = k41[j];
            kr0[j*4]=a.x; kr0[j*4+1]=a.y; kr0[j*4+2]=a.z; kr0[j*4+3]=a.w;
            kr1[j*4]=c.x; kr1[j*4+1]=c.y; kr1[j*4+2]=c.z; kr1[j*4+3]=c.w;
        }
    }
    __syncthreads();
    // stage xz = invZ[v] * xt[v] into the old ks region
    const float* xbase = xt + bt*512*32 + (size_t)vc*128*32;
    for (int e = tid; e < 1024; e += 256){
        int v = e >> 3;
        float4 xv = ((const float4*)xbase)[e];
        float izv = lds[10240 + v];
        xv.x *= izv; xv.y *= izv; xv.z *= izv; xv.w *= izv;
        ((float4*)&lds[0])[e] = xv;
    }
    __syncthreads();
    // phase 2: PV partials
    float acc0[32], acc1[32];
    #pragma unroll
    for (int c = 0; c < 32; c++){ acc0[c] = 0.0f; acc1[c] = 0.0f; }
    for (int v = 0; v < 128; v++){
        const float4* q4 = (const float4*)&lds[8192 + v*16];
        float4 qA = q4[0], qB = q4[1], qC = q4[2], qD = q4[3];
        float s0 = qA.x*kr0[0] + qA.y*kr0[1] + qA.z*kr0[2] + qA.w*kr0[3]
                 + qB.x*kr0[4] + qB.y*kr0[5] + qB.z*kr0[6] + qB.w*kr0[7]
                 + qC.x*kr0[8] + qC.y*kr0[9] + qC.z*kr0[10] + qC.w*kr0[11]
                 + qD.x*kr0[12] + qD.y*kr0[13] + qD.z*kr0[14] + qD.w*kr0[15];
        float s1 = qA.x*kr1[0] + qA.y*kr1[1] + qA.z*kr1[2] + qA.w*kr1[3]
                 + qB.x*kr1[4] + qB.y*kr1[5] + qB.z*kr1[6] + qB.w*kr1[7]
                 + qC.x*kr1[8] + qC.y*kr1[9] + qC.z*kr1[10] + qC.w*kr1[11]
                 + qD.x*kr1[12] + qD.y*kr1[13] + qD.z*kr1[14] + qD.w*kr1[15];
        float p0 = __expf(fminf(s0, 80.0f));
        float p1 = __expf(fminf(s1, 80.0f));
        const float4* x4 = (const float4*)&lds[v*32];
        #pragma unroll
        for (int cq = 0; cq < 8; cq++){
            float4 xv = x4[cq];
            acc0[cq*4]   += xv.x*p0; acc1[cq*4]   += xv.x*p1;
            acc0[cq*4+1] += xv.y*p0; acc1[cq*4+1] += xv.y*p1;
            acc0[cq*4+2] += xv.z*p0; acc1[cq*4+2] += xv.z*p1;
            acc0[cq*4+3] += xv.w*p0; acc1[cq*4+3] += xv.w*p1;
        }
    }
    float* pr0 = pbuf + (size_t)vc*1572864 + (bt*512 + tid)*32;
    float* pr1 = pr0 + 256*32;
    #pragma unroll
    for (int c = 0; c < 32; c += 4){
        *(float4*)(pr0 + c) = make_float4(acc0[c], acc0[c+1], acc0[c+2], acc0[c+3]);
        *(float4*)(pr1 + c) = make_float4(acc1[c], acc1[c+1], acc1[c+2], acc1[c+3]);
    }
}

// reduce partials + gmlp + residual -> y (pre-BN), layout [bt][c][n]
__global__ __launch_bounds__(256) void k_gmlp(
    const float* __restrict__ pbuf, const float* __restrict__ xt,
    const float* __restrict__ xin, int Tin, int d, int Tout,
    const float* __restrict__ normP,
    const float* __restrict__ gw, const float* __restrict__ gb,
    float* __restrict__ y)
{
    int tid = threadIdx.x;
    int chunk = blockIdx.x, t = blockIdx.y, b = blockIdx.z;
    size_t bt = (size_t)(b*Tout + t);
    int w = chunk*256 + tid;
    float xa[32];
    #pragma unroll
    for (int cq = 0; cq < 8; cq++){
        float4 s = make_float4(0.f,0.f,0.f,0.f);
        #pragma unroll
        for (int vc = 0; vc < 4; vc++){
            float4 pv = ((const float4*)(pbuf + (size_t)vc*1572864 + (bt*512 + w)*32))[cq];
            s.x += pv.x; s.y += pv.y; s.z += pv.z; s.w += pv.w;
        }
        xa[cq*4]=s.x; xa[cq*4+1]=s.y; xa[cq*4+2]=s.z; xa[cq*4+3]=s.w;
    }
    float xw[32];
    const float4* xwr = (const float4*)(xt + (bt*512 + w)*32);
    #pragma unroll
    for (int cq = 0; cq < 8; cq++){
        float4 xv = xwr[cq];
        xw[cq*4]=xv.x; xw[cq*4+1]=xv.y; xw[cq*4+2]=xv.z; xw[cq*4+3]=xv.w;
    }
    #pragma unroll
    for (int o = 0; o < 32; o++){
        float a = gb[o];
        const float* g0 = gw + o*64;
        #pragma unroll
        for (int c = 0; c < 32; c++) a += g0[c]*xw[c] + g0[32 + c]*xa[c];
        float res = normP[o]*xin[((size_t)(b*Tin + t + d)*32 + o)*512 + w] + normP[32 + o];
        y[(bt*32 + o)*512 + w] = a + res;
    }
}

// BN batch stats -> scale/shift for next layer's reads
__global__ __launch_bounds__(256) void k_bn(const float* __restrict__ y, int Tout,
                                            const float* __restrict__ g, const float* __restrict__ bb,
                                            float* __restrict__ normPout){
    int c = blockIdx.x; int tid = threadIdx.x;
    int cnt = 8*Tout*512;
    double s = 0.0, s2 = 0.0;
    for (int e = tid; e < cnt; e += 256){
        int n = e & 511; int btq = e >> 9;
        float v = y[((size_t)btq*32 + c)*512 + n];
        s += v; s2 += (double)v*v;
    }
    __shared__ double sh[2][4];
    for (int off = 32; off; off >>= 1){ s += __shfl_down(s, off); s2 += __shfl_down(s2, off); }
    int w = tid >> 6;
    if ((tid & 63) == 0){ sh[0][w] = s; sh[1][w] = s2; }
    __syncthreads();
    if (tid == 0){
        double S = 0.0, S2 = 0.0;
        #pragma unroll
        for (int i = 0; i < 4; i++){ S += sh[0][i]; S2 += sh[1][i]; }
        float m = (float)(S/cnt);
        float var = (float)(S2/cnt) - m*m;
        float Aa = g[c]*rsqrtf(var + 1e-5f);
        normPout[c] = Aa;
        normPout[32 + c] = bb[c] - m*Aa;
    }
}

// final: relu(skip) -> relu(end1) -> end2
__global__ __launch_bounds__(256) void k_end(const float* __restrict__ skip,
                                             const float* __restrict__ w1, const float* __restrict__ b1,
                                             const float* __restrict__ w2, const float* __restrict__ b2,
                                             float* __restrict__ out){
    __shared__ float sk[16][260];
    __shared__ float hs[512][17];
    int tid = threadIdx.x; int ng = blockIdx.x; int b = blockIdx.y;
    int nb = ng*16;
    for (int e = tid; e < 4096; e += 256){
        int oc = e >> 4, nn = e & 15;
        float v = skip[((size_t)b*256 + oc)*512 + nb + nn];
        sk[nn][oc] = fmaxf(v, 0.0f);
    }
    __syncthreads();
    float a0[16], a1[16];
    #pragma unroll
    for (int i = 0; i < 16; i++){ a0[i] = b1[tid]; a1[i] = b1[tid + 256]; }
    for (int c = 0; c < 256; c += 4){
        float4 wA = *(const float4*)(w1 + tid*256 + c);
        float4 wB = *(const float4*)(w1 + (tid + 256)*256 + c);
        #pragma unroll
        for (int nn = 0; nn < 16; nn++){
            float4 s4 = *(const float4*)(&sk[nn][c]);
            a0[nn] += wA.x*s4.x + wA.y*s4.y + wA.z*s4.z + wA.w*s4.w;
            a1[nn] += wB.x*s4.x + wB.y*s4.y + wB.z*s4.z + wB.w*s4.w;
        }
    }
    #pragma unroll
    for (int nn = 0; nn < 16; nn++){
        hs[tid][nn] = fmaxf(a0[nn], 0.0f);
        hs[tid + 256][nn] = fmaxf(a1[nn], 0.0f);
    }
    __syncthreads();
    if (tid < 192){
        int od = tid >> 4, nn = tid & 15;
        float acc = b2[od];
        for (int o = 0; o < 512; o++) acc += w2[od*512 + o]*hs[o][nn];
        out[((size_t)b*12 + od)*512 + nb + nn] = acc;
    }
}

extern "C" void kernel_launch(void* const* d_in, const int* in_sizes, int n_in,
                              void* d_out, int out_size, void* d_ws, size_t ws_size,
                              hipStream_t stream)
{
    (void)in_sizes; (void)n_in; (void)out_size; (void)ws_size;
    const float* input  = (const float*)d_in[0];
    const float* gat    = (const float*)d_in[1];
    const float* start_w= (const float*)d_in[2];
    const float* start_b= (const float*)d_in[3];
    const float* filt_w = (const float*)d_in[4];
    const float* filt_b = (const float*)d_in[5];
    const float* gate_w = (const float*)d_in[6];
    const float* gate_b = (const float*)d_in[7];
    const float* skip_w = (const float*)d_in[8];
    const float* skip_b = (const float*)d_in[9];
    const float* q_w    = (const float*)d_in[10];
    const float* q_b    = (const float*)d_in[11];
    const float* k_w    = (const float*)d_in[12];
    const float* k_b    = (const float*)d_in[13];
    const float* gmlp_w = (const float*)d_in[14];
    const float* gmlp_b = (const float*)d_in[15];
    const float* bn_g   = (const float*)d_in[16];
    const float* bn_b   = (const float*)d_in[17];
    const float* end1_w = (const float*)d_in[18];
    const float* end1_b = (const float*)d_in[19];
    const float* end2_w = (const float*)d_in[20];
    const float* end2_b = (const float*)d_in[21];
    float* out = (float*)d_out;

    float* W = (float*)d_ws;
    size_t off = 0;
    float* bufA = W + off; off += (size_t)8*13*32*512;
    float* bufB = W + off; off += (size_t)8*13*32*512;
    float* xt   = W + off; off += (size_t)8*12*512*32;
    float* qbuf = W + off; off += (size_t)8*12*512*16;
    float* kbuf = W + off; off += (size_t)8*12*512*16;
    float* skip = W + off; off += (size_t)8*256*512;
    float* qe   = W + off; off += (size_t)8*512*16;
    float* ke   = W + off; off += (size_t)8*512*16;
    float* normP= W + off; off += (size_t)9*64;
    float* pbuf = W + off; off += (size_t)4*8*12*512*32;

    hipMemsetAsync(skip, 0, (size_t)8*256*512*sizeof(float), stream);
    k_init_norm<<<1, 64, 0, stream>>>(normP);
    k_emb<<<512, 256, 0, stream>>>(q_w, q_b, k_w, k_b, gat, qe, ke);
    k_start<<<6656, 256, 0, stream>>>(input, start_w, start_b, bufA);

    const int Tin[8] = {13,12,10,9,7,6,4,3};
    const int Dd[8]  = {1,2,1,2,1,2,1,2};
    float* xin = bufA; float* yb = bufB;
    for (int i = 0; i < 8; i++){
        int Ti = Tin[i], d = Dd[i], To = Ti - d;
        k_gated<<<dim3(2, To, 8), 256, 0, stream>>>(xin, Ti, d, To, normP + i*64,
            filt_w + i*2048, filt_b + i*32, gate_w + i*2048, gate_b + i*32,
            q_w + i*768, k_w + i*768, qe + i*8192, ke + i*8192, xt, qbuf, kbuf);
        k_skip<<<4096, 256, 0, stream>>>(xt, To, skip_w + i*8192, skip_b + i*256, skip);
        if (i < 7){
            k_att<<<dim3(4, To, 8), 256, 0, stream>>>(qbuf, kbuf, xt, pbuf, To);
            k_gmlp<<<dim3(2, To, 8), 256, 0, stream>>>(pbuf, xt, xin, Ti, d, To,
                normP + i*64, gmlp_w + i*2048, gmlp_b + i*32, yb);
            k_bn<<<32, 256, 0, stream>>>(yb, To, bn_g + i*32, bn_b + i*32, normP + (i+1)*64);
            float* tmp = xin; xin = yb; yb = tmp;
        }
    }
    k_end<<<dim3(32, 8), 256, 0, stream>>>(skip, end1_w, end1_b, end2_w, end2_b, out);
}

// Round 4
// 774.096 us; speedup vs baseline: 5.9812x; 2.3623x over previous
//
#include <hip/hip_runtime.h>
#include <math.h>

// Sizes: B=8, IN=2, N=512, T_IN=13, RC=DC=32, SC=256, EC=512, EMB=16, DATT=16, L=8

typedef short v4s __attribute__((ext_vector_type(4)));
typedef float v4f __attribute__((ext_vector_type(4)));
typedef unsigned short ushort_t;

#define MFMA16(a,b,c) __builtin_amdgcn_mfma_f32_16x16x16bf16_1k(a, b, c, 0, 0, 0)

__device__ inline ushort_t f2bf(float f){
    unsigned int u = __builtin_bit_cast(unsigned int, f);
    u += 0x7FFFu + ((u >> 16) & 1u);
    return (ushort_t)(u >> 16);
}

__global__ void k_init_norm(float* normP){
    int t = threadIdx.x; // 64 threads
    normP[t] = (t < 32) ? 1.0f : 0.0f;
}

// qe/ke[l][n][16] = bias + W[:,32:48] @ gat[:,n]
__global__ void k_emb(const float* __restrict__ qw, const float* __restrict__ qb,
                      const float* __restrict__ kw, const float* __restrict__ kb,
                      const float* __restrict__ gat, float* __restrict__ qe, float* __restrict__ ke){
    int idx = blockIdx.x*256 + threadIdx.x;
    const int total = 8*512*16;
    if (idx >= 2*total) return;
    bool isK = idx >= total;
    int id = isK ? idx - total : idx;
    int dq = id & 15; int n = (id >> 4) & 511; int l = id >> 13;
    const float* w = isK ? kw : qw;
    const float* bi = isK ? kb : qb;
    float acc = bi[l*16 + dq];
    const float* wrow = w + (l*16 + dq)*48 + 32;
    #pragma unroll
    for (int e = 0; e < 16; e++) acc += wrow[e] * gat[e*512 + n];
    (isK ? ke : qe)[(l*512 + n)*16 + dq] = acc;
}

// x0[b][t][c][n] = start pw
__global__ void k_start(const float* __restrict__ inp, const float* __restrict__ sw,
                        const float* __restrict__ sb, float* __restrict__ x0){
    int idx = blockIdx.x*256 + threadIdx.x;
    if (idx >= 8*13*32*512) return;
    int n = idx & 511; int c = (idx >> 9) & 31; int r = idx >> 14;
    int t = r % 13; int b = r / 13;
    float v0 = inp[((b*2 + 0)*512 + n)*13 + t];
    float v1 = inp[((b*2 + 1)*512 + n)*13 + t];
    x0[idx] = sb[c] + sw[c*2 + 0]*v0 + sw[c*2 + 1]*v1;
}

// gated dilated conv + q/k projections. thread = (n in 64, csub of 8 channels).
// outputs: xt f32 [bt][n][32], xbfT bf16 [bt][32][512], qbf/kbf bf16 [bt][n][16]
__global__ __launch_bounds__(256) void k_gated(
    const float* __restrict__ xin, int Tin, int d, int Tout,
    const float* __restrict__ normP,
    const float* __restrict__ fw, const float* __restrict__ fb,
    const float* __restrict__ gw, const float* __restrict__ gb,
    const float* __restrict__ qw, const float* __restrict__ kw,
    const float* __restrict__ qe, const float* __restrict__ ke,
    float* __restrict__ xt, ushort_t* __restrict__ xbfT,
    ushort_t* __restrict__ qbf, ushort_t* __restrict__ kbf, int do_qk)
{
    __shared__ float fws[2048];
    __shared__ float gws[2048];
    __shared__ float qws[512];
    __shared__ float kws[512];
    __shared__ float xsh[64][33];
    int tid = threadIdx.x;
    int chunk = blockIdx.x, t = blockIdx.y, b = blockIdx.z;
    size_t bt = (size_t)(b*Tout + t);
    int n0 = chunk*64;
    for (int e = tid; e < 2048; e += 256){ fws[e] = fw[e]; gws[e] = gw[e]; }
    for (int e = tid; e < 512; e += 256){
        qws[e] = qw[(e >> 5)*48 + (e & 31)];
        kws[e] = kw[(e >> 5)*48 + (e & 31)];
    }
    __syncthreads();
    int nl = tid & 63, csub = tid >> 6;
    int n = n0 + nl;
    float x0[32], x1[32];
    const float* bb0 = xin + ((size_t)(b*Tin + t)*32)*512 + n;
    const float* bb1 = xin + ((size_t)(b*Tin + t + d)*32)*512 + n;
    #pragma unroll
    for (int c = 0; c < 32; c++){
        float A = normP[c], Bc = normP[32 + c];
        x0[c] = A*bb0[(size_t)c*512] + Bc;
        x1[c] = A*bb1[(size_t)c*512] + Bc;
    }
    #pragma unroll
    for (int ci = 0; ci < 8; ci++){
        int c = csub*8 + ci;
        float fa = fb[c], ga = gb[c];
        #pragma unroll
        for (int r = 0; r < 32; r++){
            fa += fws[(c*32+r)*2]*x0[r] + fws[(c*32+r)*2+1]*x1[r];
            ga += gws[(c*32+r)*2]*x0[r] + gws[(c*32+r)*2+1]*x1[r];
        }
        float e2 = __expf(2.0f*fa);
        float th = 1.0f - 2.0f/(e2 + 1.0f);
        float sg = 1.0f/(1.0f + __expf(-ga));
        float v = th*sg;
        xsh[nl][c] = v;
        xbfT[(bt*32 + c)*512 + n] = f2bf(v);
    }
    __syncthreads();
    float xr[32];
    #pragma unroll
    for (int c = 0; c < 32; c++) xr[c] = xsh[nl][c];
    // xt write (this thread's 8 channels)
    float* xtr = xt + ((bt*512) + n)*32 + csub*8;
    *(float4*)(xtr + 0) = make_float4(xr[csub*8+0], xr[csub*8+1], xr[csub*8+2], xr[csub*8+3]);
    *(float4*)(xtr + 4) = make_float4(xr[csub*8+4], xr[csub*8+5], xr[csub*8+6], xr[csub*8+7]);
    if (do_qk){
        #pragma unroll
        for (int jj = 0; jj < 4; jj++){
            int j = csub*4 + jj;
            float qa = qe[n*16 + j], ka = ke[n*16 + j];
            #pragma unroll
            for (int c = 0; c < 32; c++){ qa += qws[j*32 + c]*xr[c]; ka += kws[j*32 + c]*xr[c]; }
            qbf[(bt*512 + n)*16 + j] = f2bf(qa*0.25f);
            kbf[(bt*512 + n)*16 + j] = f2bf(ka);
        }
    }
}

// skip accumulation (last time column only). skip layout [b][n][256].
__global__ __launch_bounds__(256) void k_skip(
    const float* __restrict__ xt, int Tout,
    const float* __restrict__ sw, const float* __restrict__ sb,
    float* __restrict__ skip)
{
    int oc = threadIdx.x;
    int n = blockIdx.x, b = blockIdx.y;
    const float* xr = xt + (((size_t)(b*Tout + Tout-1)*512) + n)*32;
    const float* wr = sw + oc*32;
    float acc = sb[oc];
    #pragma unroll
    for (int c = 0; c < 32; c++) acc += wr[c]*xr[c];
    skip[((size_t)b*512 + n)*256 + oc] += acc;
}

// Fused MFMA attention + gmlp + residual + BN-partials. One block per bt, 512 threads (8 waves).
__global__ __launch_bounds__(512) void k_att_mfma(
    const ushort_t* __restrict__ qbf, const ushort_t* __restrict__ kbf,
    const ushort_t* __restrict__ xbfT,
    const float* __restrict__ xin, int Tin, int d, int Tout,
    const float* __restrict__ normP,
    const float* __restrict__ gw, const float* __restrict__ gb,
    float* __restrict__ y, float* __restrict__ bnpart)
{
    __shared__ ushort_t KQ[512*20];   // K (pass A), restaged with Q (pass B); row stride 20
    __shared__ ushort_t XT[32*520];   // x^T bf16, row stride 520
    __shared__ float rz[512];
    __shared__ float bnsh[512];       // [wave][32 c][2]
    int tid = threadIdx.x;
    int t = blockIdx.x, b = blockIdx.y;
    size_t bt = (size_t)(b*Tout + t);
    int l = tid & 63, wid = tid >> 6;
    int m16 = l & 15, g4 = (l >> 4)*4;

    const ushort_t* qg = qbf + bt*8192;
    const ushort_t* kg = kbf + bt*8192;
    // stage K + XT
    {
        int r = tid;
        const uint2* src = (const uint2*)(kg + r*16);
        uint2* dst = (uint2*)(KQ + r*20);
        dst[0] = src[0]; dst[1] = src[1]; dst[2] = src[2]; dst[3] = src[3];
        int c = tid >> 4, seg = tid & 15;
        const uint4* xs = (const uint4*)(xbfT + bt*16384 + c*512 + seg*32);
        uint4* xd = (uint4*)(XT + c*520 + seg*32);
        xd[0] = xs[0]; xd[1] = xs[1]; xd[2] = xs[2]; xd[3] = xs[3];
    }
    // gmlp weight frags (A[row=out][k=c]); part 0 = x, part 1 = xa
    v4s AG[2][2][2];
    #pragma unroll
    for (int pt = 0; pt < 2; pt++)
    #pragma unroll
    for (int ot = 0; ot < 2; ot++)
    #pragma unroll
    for (int ct = 0; ct < 2; ct++){
        float4 gv = *(const float4*)(gw + (ot*16 + m16)*64 + pt*32 + ct*16 + g4);
        v4s r; r[0] = (short)f2bf(gv.x); r[1] = (short)f2bf(gv.y);
        r[2] = (short)f2bf(gv.z); r[3] = (short)f2bf(gv.w);
        AG[pt][ot][ct] = r;
    }
    v4f gbv[2], An[2], Bn[2];
    #pragma unroll
    for (int ot = 0; ot < 2; ot++){
        gbv[ot] = *(const v4f*)(gb + ot*16 + g4);
        An[ot]  = *(const v4f*)(normP + ot*16 + g4);
        Bn[ot]  = *(const v4f*)(normP + 32 + ot*16 + g4);
    }
    v4s ones; ones[0] = (short)0x3F80; ones[1] = (short)0x3F80;
    ones[2] = (short)0x3F80; ones[3] = (short)0x3F80;
    __syncthreads();

    // ---- pass A: z[v] = sum_w exp(q_v . k_w) ----
    #pragma unroll
    for (int vi = 0; vi < 4; vi++){
        int vt = wid*4 + vi;
        v4s bq = *(const v4s*)(qg + (vt*16 + m16)*16 + g4);   // B[k=d][col=v], global (L2-hot)
        v4f cz = {0.f, 0.f, 0.f, 0.f};
        for (int wt = 0; wt < 32; wt++){
            v4s ak = *(const v4s*)(KQ + (wt*16 + m16)*20 + g4); // A[m=w][k=d]
            v4f s = MFMA16(ak, bq, ((v4f){0.f,0.f,0.f,0.f}));   // D[w][v] = s^T
            v4s p;
            #pragma unroll
            for (int i = 0; i < 4; i++) p[i] = (short)f2bf(__expf(fminf(s[i], 60.0f)));
            cz = MFMA16(ones, p, cz);                            // D[m][v] = z[v]
        }
        if (l < 16) rz[vt*16 + l] = 1.0f / cz[0];
    }
    __syncthreads();
    // restage Q into KQ
    {
        int r = tid;
        const uint2* src = (const uint2*)(qg + r*16);
        uint2* dst = (uint2*)(KQ + r*20);
        dst[0] = src[0]; dst[1] = src[1]; dst[2] = src[2]; dst[3] = src[3];
    }
    __syncthreads();

    // ---- pass B: PV + gmlp + residual + y + bn partials ----
    float bs1[2][4], bs2[2][4];
    #pragma unroll
    for (int ot = 0; ot < 2; ot++)
    #pragma unroll
    for (int i = 0; i < 4; i++){ bs1[ot][i] = 0.f; bs2[ot][i] = 0.f; }

    #pragma unroll
    for (int wi = 0; wi < 4; wi++){
        int wt = wid*4 + wi;
        v4s bk = *(const v4s*)(kg + (wt*16 + m16)*16 + g4);   // B[k=d][col=w], global
        v4f c2[2] = {{0.f,0.f,0.f,0.f},{0.f,0.f,0.f,0.f}};
        for (int vt = 0; vt < 32; vt++){
            v4s aq = *(const v4s*)(KQ + (vt*16 + m16)*20 + g4); // A[m=v][k=d]
            v4f s = MFMA16(aq, bk, ((v4f){0.f,0.f,0.f,0.f}));   // D[v][w]
            v4f rzv = *(const v4f*)(rz + vt*16 + g4);
            v4s p;
            #pragma unroll
            for (int i = 0; i < 4; i++) p[i] = (short)f2bf(__expf(fminf(s[i], 60.0f)) * rzv[i]);
            #pragma unroll
            for (int ct = 0; ct < 2; ct++){
                v4s ax = *(const v4s*)(XT + (ct*16 + m16)*520 + vt*16 + g4); // A[m=c][k=v]
                c2[ct] = MFMA16(ax, p, c2[ct]);                  // D[c][w] = xa^T
            }
        }
        // gmlp: out = G0.x + G1.xa + gb ; then + residual
        v4s bxa[2], bx[2];
        #pragma unroll
        for (int ct = 0; ct < 2; ct++){
            v4s r;
            #pragma unroll
            for (int i = 0; i < 4; i++) r[i] = (short)f2bf(c2[ct][i]);
            bxa[ct] = r;
            v4s q;
            #pragma unroll
            for (int i = 0; i < 4; i++) q[i] = (short)XT[(ct*16 + g4 + i)*520 + wt*16 + m16];
            bx[ct] = q;
        }
        v4f c3[2];
        #pragma unroll
        for (int ot = 0; ot < 2; ot++){
            c3[ot] = gbv[ot];
            #pragma unroll
            for (int ct = 0; ct < 2; ct++){
                c3[ot] = MFMA16(AG[1][ot][ct], bxa[ct], c3[ot]);
                c3[ot] = MFMA16(AG[0][ot][ct], bx[ct],  c3[ot]);
            }
        }
        int wg = wt*16 + m16;
        const float* resbase = xin + ((size_t)(b*Tin + t + d)*32)*512 + wg;
        float* ybase = y + (bt*32)*512 + wg;
        #pragma unroll
        for (int ot = 0; ot < 2; ot++){
            #pragma unroll
            for (int i = 0; i < 4; i++){
                int out = ot*16 + g4 + i;
                float yv = c3[ot][i] + An[ot][i]*resbase[(size_t)out*512] + Bn[ot][i];
                ybase[(size_t)out*512] = yv;
                bs1[ot][i] += yv; bs2[ot][i] += yv*yv;
            }
        }
    }
    // butterfly over the 16 w-lanes
    #pragma unroll
    for (int off = 1; off <= 8; off <<= 1){
        #pragma unroll
        for (int ot = 0; ot < 2; ot++)
        #pragma unroll
        for (int i = 0; i < 4; i++){
            bs1[ot][i] += __shfl_xor(bs1[ot][i], off);
            bs2[ot][i] += __shfl_xor(bs2[ot][i], off);
        }
    }
    if (m16 == 0){
        #pragma unroll
        for (int ot = 0; ot < 2; ot++)
        #pragma unroll
        for (int i = 0; i < 4; i++){
            int c = ot*16 + g4 + i;
            bnsh[(wid*32 + c)*2 + 0] = bs1[ot][i];
            bnsh[(wid*32 + c)*2 + 1] = bs2[ot][i];
        }
    }
    __syncthreads();
    if (tid < 64){
        int c = tid & 31, p = tid >> 5;
        float s = 0.f;
        #pragma unroll
        for (int w = 0; w < 8; w++) s += bnsh[(w*32 + c)*2 + p];
        bnpart[bt*64 + c*2 + p] = s;
    }
}

// finalize BN stats -> scale/shift for next layer's reads
__global__ void k_bn_fin(const float* __restrict__ bnpart, int nbt,
                         const float* __restrict__ g, const float* __restrict__ bb,
                         float* __restrict__ normPout){
    int c = threadIdx.x;
    if (c >= 32) return;
    float s = 0.f, s2 = 0.f;
    for (int ibt = 0; ibt < nbt; ibt++){
        s  += bnpart[ibt*64 + c*2 + 0];
        s2 += bnpart[ibt*64 + c*2 + 1];
    }
    float cnt = (float)nbt * 512.0f;
    float m = s/cnt;
    float var = s2/cnt - m*m;
    float A = g[c]*rsqrtf(var + 1e-5f);
    normPout[c] = A;
    normPout[32 + c] = bb[c] - m*A;
}

// final: relu(skip) -> relu(end1) -> end2. skip layout [b][n][256].
__global__ __launch_bounds__(256) void k_end(const float* __restrict__ skip,
                                             const float* __restrict__ w1, const float* __restrict__ b1,
                                             const float* __restrict__ w2, const float* __restrict__ b2,
                                             float* __restrict__ out){
    __shared__ float sk[16][260];
    __shared__ float hs[512][17];
    int tid = threadIdx.x; int ng = blockIdx.x; int b = blockIdx.y;
    int nb = ng*16;
    for (int e = tid; e < 4096; e += 256){
        int oc = e & 255, nn = e >> 8;
        float v = skip[((size_t)b*512 + nb + nn)*256 + oc];
        sk[nn][oc] = fmaxf(v, 0.0f);
    }
    __syncthreads();
    float a0[16], a1[16];
    #pragma unroll
    for (int i = 0; i < 16; i++){ a0[i] = b1[tid]; a1[i] = b1[tid + 256]; }
    for (int c = 0; c < 256; c += 4){
        float4 wA = *(const float4*)(w1 + tid*256 + c);
        float4 wB = *(const float4*)(w1 + (tid + 256)*256 + c);
        #pragma unroll
        for (int nn = 0; nn < 16; nn++){
            float4 s4 = *(const float4*)(&sk[nn][c]);
            a0[nn] += wA.x*s4.x + wA.y*s4.y + wA.z*s4.z + wA.w*s4.w;
            a1[nn] += wB.x*s4.x + wB.y*s4.y + wB.z*s4.z + wB.w*s4.w;
        }
    }
    #pragma unroll
    for (int nn = 0; nn < 16; nn++){
        hs[tid][nn] = fmaxf(a0[nn], 0.0f);
        hs[tid + 256][nn] = fmaxf(a1[nn], 0.0f);
    }
    __syncthreads();
    if (tid < 192){
        int od = tid >> 4, nn = tid & 15;
        float acc = b2[od];
        for (int o = 0; o < 512; o++) acc += w2[od*512 + o]*hs[o][nn];
        out[((size_t)b*12 + od)*512 + nb + nn] = acc;
    }
}

extern "C" void kernel_launch(void* const* d_in, const int* in_sizes, int n_in,
                              void* d_out, int out_size, void* d_ws, size_t ws_size,
                              hipStream_t stream)
{
    (void)in_sizes; (void)n_in; (void)out_size; (void)ws_size;
    const float* input  = (const float*)d_in[0];
    const float* gat    = (const float*)d_in[1];
    const float* start_w= (const float*)d_in[2];
    const float* start_b= (const float*)d_in[3];
    const float* filt_w = (const float*)d_in[4];
    const float* filt_b = (const float*)d_in[5];
    const float* gate_w = (const float*)d_in[6];
    const float* gate_b = (const float*)d_in[7];
    const float* skip_w = (const float*)d_in[8];
    const float* skip_b = (const float*)d_in[9];
    const float* q_w    = (const float*)d_in[10];
    const float* q_b    = (const float*)d_in[11];
    const float* k_w    = (const float*)d_in[12];
    const float* k_b    = (const float*)d_in[13];
    const float* gmlp_w = (const float*)d_in[14];
    const float* gmlp_b = (const float*)d_in[15];
    const float* bn_g   = (const float*)d_in[16];
    const float* bn_b   = (const float*)d_in[17];
    const float* end1_w = (const float*)d_in[18];
    const float* end1_b = (const float*)d_in[19];
    const float* end2_w = (const float*)d_in[20];
    const float* end2_b = (const float*)d_in[21];
    float* out = (float*)d_out;

    float* W = (float*)d_ws;
    size_t off = 0;
    float* bufA = W + off; off += (size_t)8*13*32*512;
    float* bufB = W + off; off += (size_t)8*13*32*512;
    float* xt   = W + off; off += (size_t)8*12*512*32;
    float* skip = W + off; off += (size_t)8*512*256;
    float* qe   = W + off; off += (size_t)8*512*16;
    float* ke   = W + off; off += (size_t)8*512*16;
    float* normP= W + off; off += (size_t)9*64;
    float* bnpart = W + off; off += (size_t)96*64;
    ushort_t* xbfT = (ushort_t*)(W + off); off += (size_t)8*12*32*512/2;
    ushort_t* qbf  = (ushort_t*)(W + off); off += (size_t)8*12*512*16/2;
    ushort_t* kbf  = (ushort_t*)(W + off); off += (size_t)8*12*512*16/2;

    hipMemsetAsync(skip, 0, (size_t)8*512*256*sizeof(float), stream);
    k_init_norm<<<1, 64, 0, stream>>>(normP);
    k_emb<<<512, 256, 0, stream>>>(q_w, q_b, k_w, k_b, gat, qe, ke);
    k_start<<<6656, 256, 0, stream>>>(input, start_w, start_b, bufA);

    const int Tin[8] = {13,12,10,9,7,6,4,3};
    const int Dd[8]  = {1,2,1,2,1,2,1,2};
    float* xin = bufA; float* yb = bufB;
    for (int i = 0; i < 8; i++){
        int Ti = Tin[i], d = Dd[i], To = Ti - d;
        k_gated<<<dim3(8, To, 8), 256, 0, stream>>>(xin, Ti, d, To, normP + i*64,
            filt_w + i*2048, filt_b + i*32, gate_w + i*2048, gate_b + i*32,
            q_w + i*768, k_w + i*768, qe + i*8192, ke + i*8192,
            xt, xbfT, qbf, kbf, (i < 7) ? 1 : 0);
        k_skip<<<dim3(512, 8), 256, 0, stream>>>(xt, To, skip_w + i*8192, skip_b + i*256, skip);
        if (i < 7){
            k_att_mfma<<<dim3(To, 8), 512, 0, stream>>>(qbf, kbf, xbfT,
                xin, Ti, d, To, normP + i*64, gmlp_w + i*2048, gmlp_b + i*32, yb, bnpart);
            k_bn_fin<<<1, 32, 0, stream>>>(bnpart, 8*To, bn_g + i*32, bn_b + i*32, normP + (i+1)*64);
            float* tmp = xin; xin = yb; yb = tmp;
        }
    }
    k_end<<<dim3(32, 8), 256, 0, stream>>>(skip, end1_w, end1_b, end2_w, end2_b, out);
}